// Round 9
// baseline (251.930 us; speedup 1.0000x reference)
//
#include <hip/hip_runtime.h>
#include <hip/hip_bf16.h>
#include <math.h>

// MoE: B=2,S=1024,D=1024,E=8,H=3584, top-1 routing.
// router(+x->bf16) -> aux -> scatter
//  -> ggemm<GATHER>: g1=x@W1^T, g2=x@W2^T  (z = expert x matrix)
//  -> swiglu (g1 <- silu(g1)*g2)
//  -> ggemm<ATOMIC>: out += h@W3^T (split-K=2, exactly 2 atomic adds/address)
// GEMM: 512 threads / 8 waves, BM=256 (32 rows/wave), BN=64, BK=64.
// A in REGISTERS (2 sets, per-wave private, gathered from L2-resident bf16).
// B only in LDS (dbuf 2x8KB, XOR-swizzled), f32->bf16 via 4 rotating reg sets.
// Barriers lgkmcnt-only; vmem loads are reg-private and never drained.
// LDS ~17.5KB -> high occupancy (target 16 waves/CU) for TLP latency hiding.

#define NS 1024
#define ND 1024
#define NE 8
#define NH 3584
#define NTOK 2048

typedef float f32x4 __attribute__((ext_vector_type(4)));
typedef __bf16 bf16x8 __attribute__((ext_vector_type(8)));
typedef unsigned short u16x8 __attribute__((ext_vector_type(8)));

#define LBAR() asm volatile("s_waitcnt lgkmcnt(0)\n\ts_barrier" ::: "memory")

__device__ __forceinline__ unsigned short f2b(float f) {
  return __builtin_bit_cast(unsigned short, (__bf16)f);
}
__device__ __forceinline__ u16x8 cvt8(f32x4 a, f32x4 b) {
  u16x8 r;
  r[0] = f2b(a[0]); r[1] = f2b(a[1]); r[2] = f2b(a[2]); r[3] = f2b(a[3]);
  r[4] = f2b(b[0]); r[5] = f2b(b[1]); r[6] = f2b(b[2]); r[7] = f2b(b[3]);
  return r;
}

// ---------------- router (+ x f32 -> bf16) ----------------
__global__ __launch_bounds__(256) void router_kernel(
    const float* __restrict__ x, const float* __restrict__ Wr,
    float* __restrict__ probs, float* __restrict__ lse,
    int* __restrict__ counts, int* __restrict__ expert_of,
    unsigned short* __restrict__ xb)
{
  int n = blockIdx.x;
  int t = threadIdx.x;
  const float* xr = x + (size_t)n * ND;
  float xv[4];
#pragma unroll
  for (int j = 0; j < 4; ++j) xv[j] = xr[t + j * 256];
#pragma unroll
  for (int j = 0; j < 4; ++j)
    xb[(size_t)n * ND + t + j * 256] = f2b(xv[j]);
  float p[NE];
#pragma unroll
  for (int e = 0; e < NE; ++e) p[e] = 0.f;
#pragma unroll
  for (int j = 0; j < 4; ++j) {
    int d = t + j * 256;
#pragma unroll
    for (int e = 0; e < NE; ++e) p[e] += xv[j] * Wr[e * ND + d];
  }
#pragma unroll
  for (int e = 0; e < NE; ++e) {
#pragma unroll
    for (int o = 32; o > 0; o >>= 1) p[e] += __shfl_down(p[e], o, 64);
  }
  __shared__ float red[4][NE];
  int wid = t >> 6, lane = t & 63;
  if (lane == 0) {
#pragma unroll
    for (int e = 0; e < NE; ++e) red[wid][e] = p[e];
  }
  __syncthreads();
  if (t == 0) {
    float lg[NE];
#pragma unroll
    for (int e = 0; e < NE; ++e) lg[e] = red[0][e] + red[1][e] + red[2][e] + red[3][e];
    float m = lg[0]; int arg = 0;
#pragma unroll
    for (int e = 1; e < NE; ++e) if (lg[e] > m) { m = lg[e]; arg = e; }
    float s = 0.f, ex[NE];
#pragma unroll
    for (int e = 0; e < NE; ++e) { ex[e] = expf(lg[e] - m); s += ex[e]; }
    float inv = 1.f / s;
#pragma unroll
    for (int e = 0; e < NE; ++e) probs[n * NE + e] = ex[e] * inv;
    lse[n] = m + logf(s);
    expert_of[n] = arg;
    atomicAdd(&counts[arg], 1);
  }
}

// ---------------- aux losses + offsets ----------------
__global__ __launch_bounds__(256) void aux_offsets_kernel(
    const float* __restrict__ probs, const float* __restrict__ lse,
    const int* __restrict__ counts, int* __restrict__ offsets,
    int* __restrict__ cursors, float* __restrict__ out_aux)
{
  int t = threadIdx.x;
  float lsum = 0.f;
  for (int n = t; n < NTOK; n += 256) lsum += lse[n];
  float esum = 0.f, esq = 0.f;
  for (int i = t; i < NS * NE; i += 256) {
    float v = probs[i] + probs[NS * NE + i];
    esum += v; esq += v * v;
  }
  __shared__ float rb[3][4];
  int wid = t >> 6, lane = t & 63;
#pragma unroll
  for (int o = 32; o > 0; o >>= 1) {
    lsum += __shfl_down(lsum, o, 64);
    esum += __shfl_down(esum, o, 64);
    esq  += __shfl_down(esq, o, 64);
  }
  if (lane == 0) { rb[0][wid] = lsum; rb[1][wid] = esum; rb[2][wid] = esq; }
  __syncthreads();
  if (t == 0) {
    lsum = rb[0][0] + rb[0][1] + rb[0][2] + rb[0][3];
    esum = rb[1][0] + rb[1][1] + rb[1][2] + rb[1][3];
    esq  = rb[2][0] + rb[2][1] + rb[2][2] + rb[2][3];
    float zmean = lsum / (float)NTOK;
    float z_loss = zmean * zmean;
    const float nn = (float)(NS * NE);
    float mean = esum / nn;
    float var = (esq - esum * esum / nn) / (nn - 1.0f);
    float load_loss = var / (mean * mean);
    out_aux[0] = 1e-3f * z_loss + 1e-3f * load_loss;
    int off = 0;
#pragma unroll
    for (int e = 0; e < NE; ++e) { offsets[e] = off; cursors[e] = off; off += counts[e]; }
    offsets[NE] = off;
  }
}

// ---------------- token lists ----------------
__global__ __launch_bounds__(256) void scatter_kernel(
    const int* __restrict__ expert_of, int* __restrict__ cursors,
    int* __restrict__ token_list)
{
  int n = blockIdx.x * 256 + threadIdx.x;
  int e = expert_of[n];
  int p = atomicAdd(&cursors[e], 1);
  token_list[p] = n;
}

// ---------------- grouped GEMM: A-in-regs, B-only LDS ----------------
template<int NSTEP, int LDA, int LDW, bool GATHER, bool ATOMIC>
__global__ __launch_bounds__(512, 4) void ggemm(
    const unsigned short* __restrict__ Ab,
    const float* __restrict__ Wa, const float* __restrict__ Wb,
    const int* __restrict__ offsets, const int* __restrict__ token_list,
    unsigned short* __restrict__ ga, unsigned short* __restrict__ gb,
    float* __restrict__ outp)
{
  const int e = blockIdx.z & 7;
  const int sel = blockIdx.z >> 3;          // matrix (GATHER) | k-split
  const int base = offsets[e], cnt = offsets[e + 1] - base;
  const int m0 = blockIdx.y * 256;
  if (m0 >= cnt) return;
  const int n0 = blockIdx.x * 64;
  const float* W;
  unsigned short* g = nullptr;
  int akoff = 0;
  if constexpr (GATHER) {
    W = (sel ? Wb : Wa) + (size_t)e * ((size_t)NH * ND) + (size_t)n0 * LDW;
    g = sel ? gb : ga;
  } else {
    akoff = sel * (NSTEP * 64);
    W = Wa + (size_t)e * ((size_t)NH * ND) + (size_t)n0 * LDW + akoff;
  }

  __shared__ __align__(16) unsigned short Bs[2][4096];  // 2 x 8KB, swizzled
  __shared__ int rtk[256];

  const int t = threadIdx.x, l = t & 63, w = t >> 6;
  const int rl = l & 15, rq = l >> 4;

  if (t < 256) {
    int mc = m0 + t; if (mc > cnt - 1) mc = cnt - 1;
    rtk[t] = token_list[base + mc];
  }
  __syncthreads();

  // A fragment pointers: wave w rows w*32 + i*16 + rl (2 frags), reg-resident
  const unsigned short* aptr[2];
#pragma unroll
  for (int i = 0; i < 2; ++i) {
    int mrel = w * 32 + i * 16 + rl;
    size_t row;
    if constexpr (GATHER) {
      row = (size_t)rtk[mrel];
    } else {
      int mc = m0 + mrel; if (mc > cnt - 1) mc = cnt - 1;
      row = (size_t)(base + mc);
    }
    aptr[i] = Ab + row * LDA + akoff + rq * 8;
  }

  // B staging: thread t -> row t>>3, 8 f32 cols at (t&7)*8; swizzled 16B write
  const int br = t >> 3, bc = t & 7;
  const float* bp = W + (size_t)br * LDW + bc * 8;
  const int bw = br * 128 + ((bc ^ (br & 7)) * 16);

  bf16x8 aset[2][2][2];   // [set][frag][kk]
  f32x4 bs[4][2];         // 4 rotating B sets
  f32x4 acc[2][4] = {};

  auto loadA = [&](int s, int k) {
#pragma unroll
    for (int i = 0; i < 2; ++i)
#pragma unroll
      for (int kk = 0; kk < 2; ++kk)
        aset[s][i][kk] = *(const bf16x8*)(aptr[i] + (size_t)k * 64 + kk * 32);
  };
  auto loadB = [&](int s, int k) {
    bs[s][0] = *(const f32x4*)(bp + (size_t)k * 64);
    bs[s][1] = *(const f32x4*)(bp + (size_t)k * 64 + 4);
  };
  auto writeB = [&](int buf, int s) {
    *(u16x8*)((char*)&Bs[buf][0] + bw) = cvt8(bs[s][0], bs[s][1]);
  };
  auto domfma = [&](int buf, int s) {
#pragma unroll
    for (int kk = 0; kk < 2; ++kk) {
      bf16x8 bf[4];
#pragma unroll
      for (int j = 0; j < 4; ++j)
        bf[j] = *(const bf16x8*)((const char*)&Bs[buf][0] +
                 (j * 16 + rl) * 128 + (((kk * 4 + rq) ^ (rl & 7)) * 16));
#pragma unroll
      for (int i = 0; i < 2; ++i)
#pragma unroll
        for (int j = 0; j < 4; ++j)
          acc[i][j] = __builtin_amdgcn_mfma_f32_16x16x32_bf16(
              aset[s][i][kk], bf[j], acc[i][j], 0, 0, 0);
    }
  };

  // prologue: A(0); B sets 0,1,2; publish B(0)
  loadA(0, 0);
  loadB(0, 0); loadB(1, 1); loadB(2, 2);
  writeB(0, 0);
  LBAR();

#pragma unroll
  for (int k = 0; k < NSTEP; ++k) {
    if (k + 1 < NSTEP) loadA((k + 1) & 1, k + 1);
    if (k + 3 < NSTEP) loadB((k + 3) & 3, k + 3);
    domfma(k & 1, k & 1);
    if (k + 1 < NSTEP) {
      writeB((k + 1) & 1, (k + 1) & 3);   // set loaded 2 iters ago
      LBAR();
    }
  }

  // epilogue
#pragma unroll
  for (int i = 0; i < 2; ++i)
#pragma unroll
    for (int r = 0; r < 4; ++r) {
      int mrel = w * 32 + i * 16 + rq * 4 + r;
      int m = m0 + mrel;
      if (m < cnt) {
#pragma unroll
        for (int j = 0; j < 4; ++j) {
          int col = n0 + j * 16 + rl;
          float v = acc[i][j][r];
          if constexpr (ATOMIC) {
            atomicAdd(&outp[(size_t)rtk[mrel] * ND + col], v);
          } else {
            g[(size_t)(base + m) * NH + col] = f2b(v);
          }
        }
      }
    }
}

// ---------------- SwiGLU in-place: g1 <- silu(g1)*g2 ----------------
__global__ __launch_bounds__(256) void swiglu_kernel(
    unsigned short* __restrict__ g1, const unsigned short* __restrict__ g2)
{
  size_t i = ((size_t)blockIdx.x * 256 + threadIdx.x) * 8;
  u16x8 a = *(const u16x8*)(g1 + i);
  u16x8 b = *(const u16x8*)(g2 + i);
  u16x8 o;
#pragma unroll
  for (int j = 0; j < 8; ++j) {
    float av = __builtin_bit_cast(float, (unsigned int)a[j] << 16);
    float bv = __builtin_bit_cast(float, (unsigned int)b[j] << 16);
    o[j] = f2b(av / (1.f + expf(-av)) * bv);
  }
  *(u16x8*)(g1 + i) = o;
}

extern "C" void kernel_launch(void* const* d_in, const int* in_sizes, int n_in,
                              void* d_out, int out_size, void* d_ws, size_t ws_size,
                              hipStream_t stream)
{
  (void)in_sizes; (void)n_in; (void)out_size; (void)ws_size;
  const float* x  = (const float*)d_in[0];
  const float* Wr = (const float*)d_in[1];
  const float* W1 = (const float*)d_in[2];
  const float* W2 = (const float*)d_in[3];
  const float* W3 = (const float*)d_in[4];
  float* out = (float*)d_out;

  char* w = (char*)d_ws;
  float* probs    = (float*)(w + 0);        // 65536 B
  float* lse      = (float*)(w + 65536);    // 8192 B
  int* counts     = (int*)(w + 73728);      // 32 B
  int* cursors    = (int*)(w + 73760);      // 32 B
  int* offsets    = (int*)(w + 73792);      // 64 B
  int* expert_of  = (int*)(w + 73856);      // 8192 B
  int* token_list = (int*)(w + 82048);      // 8192 B
  unsigned short* g1 = (unsigned short*)(w + 131072);            // 14680064 B (-> h)
  unsigned short* g2 = g1 + (size_t)NTOK * NH;                   // 14680064 B
  unsigned short* xb = (unsigned short*)((char*)g2 + (size_t)NTOK * NH * 2); // 4 MB

  hipMemsetAsync(counts, 0, 32, stream);
  hipMemsetAsync(out, 0, (size_t)NTOK * ND * sizeof(float), stream);
  router_kernel<<<NTOK, 256, 0, stream>>>(x, Wr, probs, lse, counts, expert_of, xb);
  aux_offsets_kernel<<<1, 256, 0, stream>>>(probs, lse, counts, offsets, cursors,
                                            out + (size_t)NTOK * ND);
  scatter_kernel<<<NTOK / 256, 256, 0, stream>>>(expert_of, cursors, token_list);
  // g1 = x@W1^T, g2 = x@W2^T   (z = expert(8) x matrix(2))
  ggemm<ND / 64, ND, ND, true, false><<<dim3(NH / 64, 2, 16), 512, 0, stream>>>(
      xb, W1, W2, offsets, token_list, g1, g2, nullptr);
  swiglu_kernel<<<(NTOK * NH) / (256 * 8), 256, 0, stream>>>(g1, g2);
  // out += h@W3^T   (z = expert(8) x ksplit(2)); exactly 2 atomics/address
  ggemm<(NH / 2) / 64, NH, NH, false, true><<<dim3(ND / 64, 2, 16), 512, 0, stream>>>(
      g1, W3, nullptr, offsets, token_list, nullptr, nullptr, out);
}

// Round 10
// 231.030 us; speedup vs baseline: 1.0905x; 1.0905x over previous
//
#include <hip/hip_runtime.h>
#include <hip/hip_bf16.h>
#include <math.h>

// MoE: B=2,S=1024,D=1024,E=8,H=3584, top-1 routing.
// router(+x->bf16) -> aux -> scatter
//  -> gemm12: h = silu(x@W1^T)*(x@W2^T) fused, SwiGLU epilogue
//  -> gemm3 : out += h@W3^T (split-K=2, exactly 2 atomic adds/address)
// Key change (r10): weight loads issue 512B-contiguous HBM requests.
// BK=128: each wave-instr reads 2 rows x 512B (lane halves). BM=256, BN=64,
// 512 thr / 8 waves (4M x 2N). A: single-buffer 64KB LDS via global_load_lds
// (swizzled source, 256B L2 requests). B: 3-deep reg sets -> XOR-swizzled
// dbuf LDS. Per iter: domfma -> LBAR -> stageA -> writeB -> loadB -> CBAR(n)
// (retire A-DMA, keep newest B-set in flight across the barrier).

#define NS 1024
#define ND 1024
#define NE 8
#define NH 3584
#define NTOK 2048

typedef float f32x4 __attribute__((ext_vector_type(4)));
typedef __bf16 bf16x8 __attribute__((ext_vector_type(8)));
typedef unsigned short u16x4 __attribute__((ext_vector_type(4)));

#define LBAR()  asm volatile("s_waitcnt lgkmcnt(0)\n\ts_barrier" ::: "memory")
#define CBAR(N) asm volatile("s_waitcnt vmcnt(" #N ") lgkmcnt(0)\n\ts_barrier" ::: "memory")

__device__ __forceinline__ unsigned short f2b(float f) {
  return __builtin_bit_cast(unsigned short, (__bf16)f);
}
__device__ __forceinline__ u16x4 cvt4(f32x4 v) {
  u16x4 r;
  r[0] = f2b(v[0]); r[1] = f2b(v[1]); r[2] = f2b(v[2]); r[3] = f2b(v[3]);
  return r;
}
__device__ __forceinline__ void gl_lds16(const void* g, void* l) {
  __builtin_amdgcn_global_load_lds(
      (const __attribute__((address_space(1))) unsigned int*)g,
      (__attribute__((address_space(3))) unsigned int*)l, 16, 0, 0);
}

// ---------------- router (+ x f32 -> bf16) ----------------
__global__ __launch_bounds__(256) void router_kernel(
    const float* __restrict__ x, const float* __restrict__ Wr,
    float* __restrict__ probs, float* __restrict__ lse,
    int* __restrict__ counts, int* __restrict__ expert_of,
    unsigned short* __restrict__ xb)
{
  int n = blockIdx.x;
  int t = threadIdx.x;
  const float* xr = x + (size_t)n * ND;
  float xv[4];
#pragma unroll
  for (int j = 0; j < 4; ++j) xv[j] = xr[t + j * 256];
#pragma unroll
  for (int j = 0; j < 4; ++j)
    xb[(size_t)n * ND + t + j * 256] = f2b(xv[j]);
  float p[NE];
#pragma unroll
  for (int e = 0; e < NE; ++e) p[e] = 0.f;
#pragma unroll
  for (int j = 0; j < 4; ++j) {
    int d = t + j * 256;
#pragma unroll
    for (int e = 0; e < NE; ++e) p[e] += xv[j] * Wr[e * ND + d];
  }
#pragma unroll
  for (int e = 0; e < NE; ++e) {
#pragma unroll
    for (int o = 32; o > 0; o >>= 1) p[e] += __shfl_down(p[e], o, 64);
  }
  __shared__ float red[4][NE];
  int wid = t >> 6, lane = t & 63;
  if (lane == 0) {
#pragma unroll
    for (int e = 0; e < NE; ++e) red[wid][e] = p[e];
  }
  __syncthreads();
  if (t == 0) {
    float lg[NE];
#pragma unroll
    for (int e = 0; e < NE; ++e) lg[e] = red[0][e] + red[1][e] + red[2][e] + red[3][e];
    float m = lg[0]; int arg = 0;
#pragma unroll
    for (int e = 1; e < NE; ++e) if (lg[e] > m) { m = lg[e]; arg = e; }
    float s = 0.f, ex[NE];
#pragma unroll
    for (int e = 0; e < NE; ++e) { ex[e] = expf(lg[e] - m); s += ex[e]; }
    float inv = 1.f / s;
#pragma unroll
    for (int e = 0; e < NE; ++e) probs[n * NE + e] = ex[e] * inv;
    lse[n] = m + logf(s);
    expert_of[n] = arg;
    atomicAdd(&counts[arg], 1);
  }
}

// ---------------- aux losses + offsets ----------------
__global__ __launch_bounds__(256) void aux_offsets_kernel(
    const float* __restrict__ probs, const float* __restrict__ lse,
    const int* __restrict__ counts, int* __restrict__ offsets,
    int* __restrict__ cursors, float* __restrict__ out_aux)
{
  int t = threadIdx.x;
  float lsum = 0.f;
  for (int n = t; n < NTOK; n += 256) lsum += lse[n];
  float esum = 0.f, esq = 0.f;
  for (int i = t; i < NS * NE; i += 256) {
    float v = probs[i] + probs[NS * NE + i];
    esum += v; esq += v * v;
  }
  __shared__ float rb[3][4];
  int wid = t >> 6, lane = t & 63;
#pragma unroll
  for (int o = 32; o > 0; o >>= 1) {
    lsum += __shfl_down(lsum, o, 64);
    esum += __shfl_down(esum, o, 64);
    esq  += __shfl_down(esq, o, 64);
  }
  if (lane == 0) { rb[0][wid] = lsum; rb[1][wid] = esum; rb[2][wid] = esq; }
  __syncthreads();
  if (t == 0) {
    lsum = rb[0][0] + rb[0][1] + rb[0][2] + rb[0][3];
    esum = rb[1][0] + rb[1][1] + rb[1][2] + rb[1][3];
    esq  = rb[2][0] + rb[2][1] + rb[2][2] + rb[2][3];
    float zmean = lsum / (float)NTOK;
    float z_loss = zmean * zmean;
    const float nn = (float)(NS * NE);
    float mean = esum / nn;
    float var = (esq - esum * esum / nn) / (nn - 1.0f);
    float load_loss = var / (mean * mean);
    out_aux[0] = 1e-3f * z_loss + 1e-3f * load_loss;
    int off = 0;
#pragma unroll
    for (int e = 0; e < NE; ++e) { offsets[e] = off; cursors[e] = off; off += counts[e]; }
    offsets[NE] = off;
  }
}

// ---------------- token lists ----------------
__global__ __launch_bounds__(256) void scatter_kernel(
    const int* __restrict__ expert_of, int* __restrict__ cursors,
    int* __restrict__ token_list)
{
  int n = blockIdx.x * 256 + threadIdx.x;
  int e = expert_of[n];
  int p = atomicAdd(&cursors[e], 1);
  token_list[p] = n;
}

// ---------------- fused GEMM12 + SwiGLU ----------------
__global__ __launch_bounds__(512, 2) void moe_gemm12(
    const unsigned short* __restrict__ xb, const float* __restrict__ W1f,
    const float* __restrict__ W2f, const int* __restrict__ offsets,
    const int* __restrict__ token_list, unsigned short* __restrict__ h)
{
  const int e = blockIdx.z;
  const int base = offsets[e], cnt = offsets[e + 1] - base;
  const int m0 = blockIdx.y * 256;
  if (m0 >= cnt) return;
  const int n0 = blockIdx.x * 64;
  const float* W1p = W1f + (size_t)e * NH * ND + (size_t)n0 * ND;
  const float* W2p = W2f + (size_t)e * NH * ND + (size_t)n0 * ND;

  __shared__ __align__(16) unsigned short As[256 * 128];      // 64 KB single buf
  __shared__ __align__(16) unsigned short B1s[2][64 * 128];   // 32 KB dbuf
  __shared__ __align__(16) unsigned short B2s[2][64 * 128];   // 32 KB dbuf
  __shared__ int rtk[256];

  const int t = threadIdx.x, l = t & 63, w = t >> 6;
  const int rl = l & 15, rq = l >> 4;

  if (t < 256) {
    int mc = m0 + t; if (mc > cnt - 1) mc = cnt - 1;
    rtk[t] = token_list[base + mc];
  }
  __syncthreads();

  // A DMA: wave w stages rows w*32..+31 (8 instrs x 4 rows x 256B).
  // LDS dest linear; source 16B-block pre-swizzled by ^(row&7).
  const unsigned short* aSrc[8];
#pragma unroll
  for (int i = 0; i < 8; ++i) {
    int row = w * 32 + i * 4 + (l >> 4);
    int sblk = (l & 15) ^ (row & 7);
    aSrc[i] = xb + (size_t)rtk[row] * ND + sblk * 8;
  }
  char* aDst = (char*)As + w * 8192;
  auto stageA = [&](int k) {
#pragma unroll
    for (int i = 0; i < 8; ++i)
      gl_lds16(aSrc[i] + k * 128, aDst + i * 1024);
  };

  // B: per wave 4 instrs/matrix, each 2 rows x 512B contiguous (lane halves)
  const float* b1p[4]; const float* b2p[4]; int bwb[4];
#pragma unroll
  for (int i = 0; i < 4; ++i) {
    int row = w * 8 + i * 2 + (l >> 5);
    b1p[i] = W1p + (size_t)row * ND + (l & 31) * 4;
    b2p[i] = W2p + (size_t)row * ND + (l & 31) * 4;
    int c32 = l & 31;
    bwb[i] = row * 256 + (((c32 >> 1) ^ (row & 7)) << 4) + ((c32 & 1) << 3);
  }
  f32x4 bs1[3][4], bs2[3][4];
  auto loadB = [&](int s, int k) {
#pragma unroll
    for (int i = 0; i < 4; ++i) {
      bs1[s][i] = *(const f32x4*)(b1p[i] + k * 128);
      bs2[s][i] = *(const f32x4*)(b2p[i] + k * 128);
    }
  };
  auto writeB = [&](int buf, int s) {
#pragma unroll
    for (int i = 0; i < 4; ++i) {
      *(u16x4*)((char*)&B1s[buf][0] + bwb[i]) = cvt4(bs1[s][i]);
      *(u16x4*)((char*)&B2s[buf][0] + bwb[i]) = cvt4(bs2[s][i]);
    }
  };

  const int awrow = (w >> 1) * 64;   // 4 M-groups of 64 rows
  const int bwcol = (w & 1) * 32;    // 2 N-groups of 32 cols
  f32x4 acc1[4][2] = {}, acc2[4][2] = {};

  auto domfma = [&](int buf) {
#pragma unroll
    for (int kk = 0; kk < 4; ++kk) {
      const int blk = ((kk * 4 + rq) ^ (rl & 7)) << 4;
      bf16x8 af[4], f1[2], f2[2];
#pragma unroll
      for (int i = 0; i < 4; ++i)
        af[i] = *(const bf16x8*)((const char*)As + (awrow + i * 16 + rl) * 256 + blk);
#pragma unroll
      for (int j = 0; j < 2; ++j) {
        f1[j] = *(const bf16x8*)((const char*)&B1s[buf][0] + (bwcol + j * 16 + rl) * 256 + blk);
        f2[j] = *(const bf16x8*)((const char*)&B2s[buf][0] + (bwcol + j * 16 + rl) * 256 + blk);
      }
#pragma unroll
      for (int i = 0; i < 4; ++i)
#pragma unroll
        for (int j = 0; j < 2; ++j) {
          acc1[i][j] = __builtin_amdgcn_mfma_f32_16x16x32_bf16(af[i], f1[j], acc1[i][j], 0, 0, 0);
          acc2[i][j] = __builtin_amdgcn_mfma_f32_16x16x32_bf16(af[i], f2[j], acc2[i][j], 0, 0, 0);
        }
    }
  };

  const int NSTEP = ND / 128;  // 8
  stageA(0);
  loadB(0, 0); loadB(1, 1); loadB(2, 2);
  writeB(0, 0);                // implicit vmcnt retires DMA(0)+set0; sets1,2 fly
  LBAR();
#pragma unroll
  for (int k = 0; k < NSTEP; ++k) {
    domfma(k & 1);
    if (k + 1 == NSTEP) break;
    LBAR();                            // all waves done reading As
    stageA(k + 1);                     // 8 DMA
    writeB((k + 1) & 1, (k + 1) % 3);  // set loaded 2 iters ago (retired)
    if (k + 3 < NSTEP) {
      loadB((k + 3) % 3, k + 3);       // 8 loads, newest
      CBAR(8);                         // retire A-DMA; keep newest B-set
    } else {
      CBAR(0);
    }
  }

  // SwiGLU epilogue
#pragma unroll
  for (int i = 0; i < 4; ++i)
#pragma unroll
    for (int r = 0; r < 4; ++r) {
      int mrow = awrow + i * 16 + rq * 4 + r;
      int m = m0 + mrow;
      if (m < cnt) {
#pragma unroll
        for (int j = 0; j < 2; ++j) {
          int col = n0 + bwcol + j * 16 + rl;
          float g1 = acc1[i][j][r], g2 = acc2[i][j][r];
          float hv = g1 / (1.f + expf(-g1)) * g2;
          h[(size_t)(base + m) * NH + col] = f2b(hv);
        }
      }
    }
}

// ---------------- GEMM3: out += h @ W3^T (split-K=2, atomicAdd) ----------------
__global__ __launch_bounds__(512, 2) void moe_gemm3(
    const unsigned short* __restrict__ hsrc, const float* __restrict__ W3f,
    const int* __restrict__ offsets, const int* __restrict__ token_list,
    float* __restrict__ outp)
{
  const int e = blockIdx.z & 7;
  const int sel = blockIdx.z >> 3;
  const int koff = sel * (NH / 2);   // 1792 elements
  const int base = offsets[e], cnt = offsets[e + 1] - base;
  const int m0 = blockIdx.y * 256;
  if (m0 >= cnt) return;
  const int n0 = blockIdx.x * 64;
  const float* W3p = W3f + (size_t)e * ND * NH + (size_t)n0 * NH + koff;

  __shared__ __align__(16) unsigned short As[256 * 128];    // 64 KB
  __shared__ __align__(16) unsigned short Bs[2][64 * 128];  // 32 KB
  __shared__ int rtk[256];

  const int t = threadIdx.x, l = t & 63, w = t >> 6;
  const int rl = l & 15, rq = l >> 4;

  if (t < 256) {
    int mc = m0 + t; if (mc > cnt - 1) mc = cnt - 1;
    rtk[t] = token_list[base + mc];
  }
  __syncthreads();

  const unsigned short* aSrc[8];
#pragma unroll
  for (int i = 0; i < 8; ++i) {
    int row = w * 32 + i * 4 + (l >> 4);
    int mc = m0 + row; if (mc > cnt - 1) mc = cnt - 1;
    int sblk = (l & 15) ^ (row & 7);
    aSrc[i] = hsrc + (size_t)(base + mc) * NH + koff + sblk * 8;
  }
  char* aDst = (char*)As + w * 8192;
  auto stageA = [&](int k) {
#pragma unroll
    for (int i = 0; i < 8; ++i)
      gl_lds16(aSrc[i] + k * 128, aDst + i * 1024);
  };

  const float* bp[4]; int bwb[4];
#pragma unroll
  for (int i = 0; i < 4; ++i) {
    int row = w * 8 + i * 2 + (l >> 5);
    bp[i] = W3p + (size_t)row * NH + (l & 31) * 4;
    int c32 = l & 31;
    bwb[i] = row * 256 + (((c32 >> 1) ^ (row & 7)) << 4) + ((c32 & 1) << 3);
  }
  f32x4 bs[3][4];
  auto loadB = [&](int s, int k) {
#pragma unroll
    for (int i = 0; i < 4; ++i) bs[s][i] = *(const f32x4*)(bp[i] + k * 128);
  };
  auto writeB = [&](int buf, int s) {
#pragma unroll
    for (int i = 0; i < 4; ++i)
      *(u16x4*)((char*)&Bs[buf][0] + bwb[i]) = cvt4(bs[s][i]);
  };

  const int awrow = (w >> 1) * 64;
  const int bwcol = (w & 1) * 32;
  f32x4 acc[4][2] = {};

  auto domfma = [&](int buf) {
#pragma unroll
    for (int kk = 0; kk < 4; ++kk) {
      const int blk = ((kk * 4 + rq) ^ (rl & 7)) << 4;
      bf16x8 af[4], bf[2];
#pragma unroll
      for (int i = 0; i < 4; ++i)
        af[i] = *(const bf16x8*)((const char*)As + (awrow + i * 16 + rl) * 256 + blk);
#pragma unroll
      for (int j = 0; j < 2; ++j)
        bf[j] = *(const bf16x8*)((const char*)&Bs[buf][0] + (bwcol + j * 16 + rl) * 256 + blk);
#pragma unroll
      for (int i = 0; i < 4; ++i)
#pragma unroll
        for (int j = 0; j < 2; ++j)
          acc[i][j] = __builtin_amdgcn_mfma_f32_16x16x32_bf16(af[i], bf[j], acc[i][j], 0, 0, 0);
    }
  };

  const int NSTEP = (NH / 2) / 128;  // 14
  stageA(0);
  loadB(0, 0); loadB(1, 1); loadB(2, 2);
  writeB(0, 0);
  LBAR();
#pragma unroll
  for (int k = 0; k < NSTEP; ++k) {
    domfma(k & 1);
    if (k + 1 == NSTEP) break;
    LBAR();
    stageA(k + 1);
    writeB((k + 1) & 1, (k + 1) % 3);
    if (k + 3 < NSTEP) {
      loadB((k + 3) % 3, k + 3);       // 4 loads, newest
      CBAR(4);                         // retire A-DMA; keep newest B-set
    } else {
      CBAR(0);
    }
  }

#pragma unroll
  for (int i = 0; i < 4; ++i)
#pragma unroll
    for (int r = 0; r < 4; ++r) {
      int mrow = awrow + i * 16 + rq * 4 + r;
      int m = m0 + mrow;
      if (m < cnt) {
        int tok = rtk[mrow];
#pragma unroll
        for (int j = 0; j < 2; ++j) {
          int col = n0 + bwcol + j * 16 + rl;
          atomicAdd(&outp[(size_t)tok * ND + col], acc[i][j][r]);
        }
      }
    }
}

extern "C" void kernel_launch(void* const* d_in, const int* in_sizes, int n_in,
                              void* d_out, int out_size, void* d_ws, size_t ws_size,
                              hipStream_t stream)
{
  (void)in_sizes; (void)n_in; (void)out_size; (void)ws_size;
  const float* x  = (const float*)d_in[0];
  const float* Wr = (const float*)d_in[1];
  const float* W1 = (const float*)d_in[2];
  const float* W2 = (const float*)d_in[3];
  const float* W3 = (const float*)d_in[4];
  float* out = (float*)d_out;

  char* w = (char*)d_ws;
  float* probs    = (float*)(w + 0);        // 65536 B
  float* lse      = (float*)(w + 65536);    // 8192 B
  int* counts     = (int*)(w + 73728);      // 32 B
  int* cursors    = (int*)(w + 73760);      // 32 B
  int* offsets    = (int*)(w + 73792);      // 64 B
  int* expert_of  = (int*)(w + 73856);      // 8192 B
  int* token_list = (int*)(w + 82048);      // 8192 B
  unsigned short* h  = (unsigned short*)(w + 131072);            // 14680064 B
  unsigned short* xb = (unsigned short*)(w + 131072 + 14680064); // 4194304 B

  hipMemsetAsync(counts, 0, 32, stream);
  hipMemsetAsync(out, 0, (size_t)NTOK * ND * sizeof(float), stream);
  router_kernel<<<NTOK, 256, 0, stream>>>(x, Wr, probs, lse, counts, expert_of, xb);
  aux_offsets_kernel<<<1, 256, 0, stream>>>(probs, lse, counts, offsets, cursors,
                                            out + (size_t)NTOK * ND);
  scatter_kernel<<<NTOK / 256, 256, 0, stream>>>(expert_of, cursors, token_list);
  moe_gemm12<<<dim3(NH / 64, 2, NE), 512, 0, stream>>>(
      xb, W1, W2, offsets, token_list, h);
  moe_gemm3<<<dim3(ND / 64, 2, NE * 2), 512, 0, stream>>>(
      h, W3, offsets, token_list, out);
}